// Round 12
// baseline (423.850 us; speedup 1.0000x reference)
//
#include <hip/hip_runtime.h>
#include <stdint.h>

#define T_TOKENS 8192
#define D_DIM 1024
#define H_DIM 2048
#define E_NUM 8
#define MAXP 18432         // pairs padded to 256/expert
#define MAXT 72            // max sum of per-expert ceil(cnt/256)
#define NCHUNK 32          // 8192/256 token chunks

typedef __attribute__((ext_vector_type(8))) short short8;
typedef __attribute__((ext_vector_type(4))) float f32x4;
typedef __attribute__((ext_vector_type(8))) unsigned short u16x8;

__device__ __forceinline__ unsigned short f2bf(float f) {
  union { float f; uint32_t u; } v; v.f = f;
  uint32_t r = (v.u + 0x7fffu + ((v.u >> 16) & 1u)) >> 16;
  return (unsigned short)r;
}

__device__ __forceinline__ float bf2f(unsigned short u) {
  union { uint32_t u; float f; } v; v.u = ((uint32_t)u) << 16;
  return v.f;
}

__device__ __forceinline__ void gload16(const void* g, void* l) {
  __builtin_amdgcn_global_load_lds((const __attribute__((address_space(1))) void*)g,
                                   (__attribute__((address_space(3))) void*)l, 16, 0, 0);
}

// ---------------- router: logits (f64 accum), top-2, softmax, + fused x->bf16 cast ----------------
__global__ void router_kernel(const float* __restrict__ x, const float* __restrict__ Wg,
                              int* __restrict__ tok_e01, float* __restrict__ tok_w,
                              unsigned short* __restrict__ xb) {
  __shared__ float wgT[E_NUM * D_DIM];
  int tid = threadIdx.x;
  for (int i = tid; i < D_DIM * E_NUM; i += 256) {
    int e = i >> 10, d = i & 1023;
    wgT[e * D_DIM + d] = Wg[d * E_NUM + e];
  }
  __syncthreads();
  int wid = tid >> 6, lane = tid & 63;
  int t = blockIdx.x * 4 + wid;
  const float* xr = x + (size_t)t * D_DIM;
  unsigned short* xbr = xb + (size_t)t * D_DIM;
  double acc[E_NUM];
#pragma unroll
  for (int e = 0; e < E_NUM; e++) acc[e] = 0.0;
  for (int i = 0; i < D_DIM / 64; i++) {
    float xf = xr[i * 64 + lane];
    xbr[i * 64 + lane] = f2bf(xf);          // fused cast_x
    double xv = (double)xf;
#pragma unroll
    for (int e = 0; e < E_NUM; e++) acc[e] += xv * (double)wgT[e * D_DIM + i * 64 + lane];
  }
#pragma unroll
  for (int e = 0; e < E_NUM; e++) {
    double v = acc[e];
#pragma unroll
    for (int off = 32; off >= 1; off >>= 1) v += __shfl_xor(v, off);
    acc[e] = v;
  }
  if (lane == 0) {
    int e0 = 0; double l0 = acc[0];
#pragma unroll
    for (int e = 1; e < E_NUM; e++) if (acc[e] > l0) { l0 = acc[e]; e0 = e; }
    int e1 = -1; double l1 = -1e300;
#pragma unroll
    for (int e = 0; e < E_NUM; e++) if (e != e0 && acc[e] > l1) { l1 = acc[e]; e1 = e; }
    float z1 = expf((float)(l1 - l0));
    float w0 = 1.f / (1.f + z1);
    float w1 = z1 * w0;
    tok_e01[t] = e0 | (e1 << 8);
    tok_w[2 * t] = w0; tok_w[2 * t + 1] = w1;
  }
}

// ---------------- hist: ballot-based chunk histograms + offsets + tile table (1 block) ----------------
__global__ void hist_kernel(const int* __restrict__ tok_e01, int* __restrict__ poffs,
                            int* __restrict__ tile2e, int* __restrict__ tile_row0,
                            int* __restrict__ chunk_base) {
  __shared__ int chist[NCHUNK][E_NUM];
  int tid = threadIdx.x, wv = tid >> 6, lane = tid & 63;  // 16 waves
#pragma unroll
  for (int half = 0; half < 2; half++) {
    int myc = 0;
#pragma unroll
    for (int it = 0; it < 4; it++) {
      int t = wv * 512 + half * 256 + it * 64 + lane;
      int p = tok_e01[t];
      int e0 = p & 255, e1 = (p >> 8) & 255;
#pragma unroll
      for (int e = 0; e < E_NUM; e++) {
        unsigned long long b0 = __ballot(e0 == e);
        unsigned long long b1 = __ballot(e1 == e);
        if (lane == e) myc += __popcll(b0) + __popcll(b1);
      }
    }
    if (lane < E_NUM) chist[wv * 2 + half][lane] = myc;
  }
  __syncthreads();
  if (tid == 0) {
    int tot[E_NUM];
    for (int e = 0; e < E_NUM; e++) {
      int s = 0;
      for (int c = 0; c < NCHUNK; c++) s += chist[c][e];
      tot[e] = s;
    }
    int po = 0, tf = 0;
    for (int e = 0; e < E_NUM; e++) {
      poffs[e] = po;
      int nt = (tot[e] + 255) >> 8;
      for (int i = 0; i < nt; i++) { tile2e[tf] = e; tile_row0[tf] = po + i * 256; tf++; }
      po += nt << 8;
    }
    for (; tf < MAXT; tf++) { tile2e[tf] = -1; tile_row0[tf] = 0; }
    for (int e = 0; e < E_NUM; e++) {
      int s = poffs[e];
      for (int c = 0; c < NCHUNK; c++) { chunk_base[c * E_NUM + e] = s; s += chist[c][e]; }
    }
  }
}

// ---------------- assign: deterministic ballot-rank, zero contended atomics ----------------
__global__ void assign_kernel(const int* __restrict__ tok_e01, const int* __restrict__ chunk_base,
                              int* __restrict__ pair_tok, int2* __restrict__ tok_pos) {
  __shared__ int wcnt[4][E_NUM];
  __shared__ int woff[4][E_NUM];
  int tid = threadIdx.x, wv = tid >> 6, lane = tid & 63;
  int t = blockIdx.x * 256 + tid;
  int p = tok_e01[t];
  int e0 = p & 255, e1 = (p >> 8) & 255;
  unsigned long long lt = (lane == 63) ? ~0ull >> 1 : (1ull << lane) - 1;
  int rank0 = 0, rank1 = 0, myc = 0;
#pragma unroll
  for (int e = 0; e < E_NUM; e++) {
    unsigned long long b0 = __ballot(e0 == e);
    unsigned long long b1 = __ballot(e1 == e);
    int n0 = __popcll(b0);
    if (e0 == e) rank0 = __popcll(b0 & lt);
    if (e1 == e) rank1 = n0 + __popcll(b1 & lt);
    if (lane == e) myc = n0 + __popcll(b1);
  }
  if (lane < E_NUM) wcnt[wv][lane] = myc;
  __syncthreads();
  if (tid < E_NUM) {
    int s = 0;
    for (int w = 0; w < 4; w++) { woff[w][tid] = s; s += wcnt[w][tid]; }
  }
  __syncthreads();
  int cb = blockIdx.x * E_NUM;
  int pos0 = chunk_base[cb + e0] + woff[wv][e0] + rank0;
  int pos1 = chunk_base[cb + e1] + woff[wv][e1] + rank1;
  pair_tok[pos0] = t;
  pair_tok[pos1] = t;
  tok_pos[t] = make_int2(pos0, pos1);
}

// ---------------- weight transpose-casts ----------------
// [E][R][C] f32 -> transposed bf16, 64x64 tiles, float4 loads, coalesced u16x8 stores.
// dst per-expert stride = e_stride ELEMENTS. cat=1: Bcat 16-col interleave (voff 0=u, 1=v).
__device__ __forceinline__ void transpose64_body(const float* __restrict__ src,
                                                 unsigned short* __restrict__ dst,
                                                 int R, int C, int cat, int voff,
                                                 int bx, int by) {
  __shared__ float tile[64][68];
  int c0 = bx * 64, r0 = by * 64;
  int tl = threadIdx.x;
  int lr = tl >> 4, lc = (tl & 15) * 4;
#pragma unroll
  for (int p = 0; p < 4; p++) {
    float4 v = *(const float4*)(src + (size_t)(r0 + p * 16 + lr) * C + c0 + lc);
    *(float4*)&tile[p * 16 + lr][lc] = v;
  }
  __syncthreads();
  int cc = tl >> 2, rchunk = (tl & 3) * 16;
  int n = c0 + cc;
  int outrow = cat ? (((n >> 4) << 5) + (n & 15) + voff * 16) : n;
  u16x8 o0, o1;
#pragma unroll
  for (int k = 0; k < 8; k++) o0[k] = f2bf(tile[rchunk + k][cc]);
#pragma unroll
  for (int k = 0; k < 8; k++) o1[k] = f2bf(tile[rchunk + 8 + k][cc]);
  unsigned short* dp = dst + (size_t)outrow * R + r0 + rchunk;
  *(u16x8*)dp = o0;
  *(u16x8*)(dp + 8) = o1;
}

// W1+W2 -> Bcat (interleaved) in ONE launch: z = e*2 + voff
__global__ void cast_w12_kernel(const float* __restrict__ W1, const float* __restrict__ W2,
                                unsigned short* __restrict__ Bcat) {
  int z = blockIdx.z;
  int e = z >> 1, voff = z & 1;
  const float* src = (voff ? W2 : W1) + (size_t)e * D_DIM * H_DIM;
  unsigned short* dst = Bcat + (size_t)e * 4096 * 1024;
  transpose64_body(src, dst, D_DIM, H_DIM, 1, voff, blockIdx.x, blockIdx.y);
}

__global__ void cast_w3_kernel(const float* __restrict__ W3, unsigned short* __restrict__ W3t) {
  int e = blockIdx.z;
  const float* src = W3 + (size_t)e * H_DIM * D_DIM;
  unsigned short* dst = W3t + (size_t)e * 2048 * 1024;
  transpose64_body(src, dst, H_DIM, D_DIM, 0, 0, blockIdx.x, blockIdx.y);
}

// ---------------- pass A: 8-phase-class 256x256 deep pipeline (fused SwiGLU via Bcat) ----------------
// VERIFIED 4-phase schedule (round 8). Do not merge phases.
__global__ __launch_bounds__(512, 2) void ffn1_kernel(
    const unsigned short* __restrict__ xb, const unsigned short* __restrict__ Bcat,
    unsigned short* __restrict__ h_buf,
    const int* __restrict__ pair_tok, const int* __restrict__ tile2e,
    const int* __restrict__ tile_row0) {
  extern __shared__ char lds[];
  char* ldsB = lds + 65536;
  const int NWG = MAXT * 16;  // 1152, %8==0
  int orig = blockIdx.x;
  int wg = (orig & 7) * (NWG >> 3) + (orig >> 3);
  int f = wg >> 4, nt = wg & 15;
  int e = tile2e[f];
  if (e < 0) return;
  int row0 = tile_row0[f];

  int tid = threadIdx.x;
  int w = tid >> 6, lane = tid & 63;
  int l15 = lane & 15, g4 = lane >> 4;
  int wr = w >> 2, wn = w & 3;

  int s0 = w * 64 + lane;
  int r0_ = s0 >> 3, c0_ = s0 & 7;
  int kc = c0_ ^ (r0_ & 7);
  const char* gA[2][2];
  const char* gB[2][2];
  const char* Bce = (const char*)Bcat + (size_t)e * 4096 * 2048;
#pragma unroll
  for (int h = 0; h < 2; h++) {
    int tokA0 = pair_tok[row0 + h * 128 + r0_];
    int tokA1 = pair_tok[row0 + h * 128 + r0_ + 64];
    gA[h][0] = (const char*)xb + (size_t)tokA0 * 2048 + kc * 16;
    gA[h][1] = (const char*)xb + (size_t)tokA1 * 2048 + kc * 16;
    gB[h][0] = Bce + (size_t)(nt * 256 + h * 128 + r0_) * 2048 + kc * 16;
    gB[h][1] = Bce + (size_t)(nt * 256 + h * 128 + r0_ + 64) * 2048 + kc * 16;
  }

  auto STG_A = [&](int kt, int h, int buf) {
    char* d = lds + buf * 32768 + h * 16384 + w * 1024;
    gload16(gA[h][0] + kt * 128, d);
    gload16(gA[h][1] + kt * 128, d + 8192);
  };
  auto STG_B = [&](int kt, int h, int buf) {
    char* d = ldsB + buf * 32768 + h * 16384 + w * 1024;
    gload16(gB[h][0] + kt * 128, d);
    gload16(gB[h][1] + kt * 128, d + 8192);
  };

  int sw = l15 & 7;
  int cbase = (sw >> 2) * 64 + ((g4 ^ (sw & 3)) * 16);
  int aRow = wr * 16384 + l15 * 128;
  int bRow = 65536 + wn * 8192 + l15 * 128;

  f32x4 acc[8][4];
#pragma unroll
  for (int i = 0; i < 8; i++)
#pragma unroll
    for (int j = 0; j < 4; j++) acc[i][j] = (f32x4){0.f, 0.f, 0.f, 0.f};

  short8 a[4][2], blo[2][2], bhi[2][2];
  auto RD_A = [&](int mq, int buf) {
    const char* base = lds + buf * 32768 + aRow + mq * 8192;
#pragma unroll
    for (int m2 = 0; m2 < 4; m2++)
#pragma unroll
      for (int ks = 0; ks < 2; ks++)
        a[m2][ks] = *(const short8*)(base + m2 * 2048 + (cbase ^ (ks << 6)));
  };
  auto RD_B = [&](short8 (&b)[2][2], int nq, int buf) {
    const char* base = lds + buf * 32768 + bRow + nq * 4096;
#pragma unroll
    for (int n2 = 0; n2 < 2; n2++)
#pragma unroll
      for (int ks = 0; ks < 2; ks++)
        b[n2][ks] = *(const short8*)(base + n2 * 2048 + (cbase ^ (ks << 6)));
  };
  auto MM = [&](int mq, short8 (&b)[2][2], int nq) {
    __builtin_amdgcn_s_setprio(1);
#pragma unroll
    for (int m2 = 0; m2 < 4; m2++)
#pragma unroll
      for (int n2 = 0; n2 < 2; n2++)
#pragma unroll
        for (int ks = 0; ks < 2; ks++)
          acc[mq * 4 + m2][nq * 2 + n2] = __builtin_amdgcn_mfma_f32_16x16x32_bf16(
              a[m2][ks], b[n2][ks], acc[mq * 4 + m2][nq * 2 + n2], 0, 0, 0);
    __builtin_amdgcn_s_setprio(0);
  };

  STG_A(0, 0, 0); STG_A(0, 1, 0); STG_B(0, 0, 0); STG_B(0, 1, 0);
  STG_B(1, 0, 1); STG_A(1, 0, 1);
  asm volatile("s_waitcnt vmcnt(4)" ::: "memory");
  __builtin_amdgcn_s_barrier();
  asm volatile("" ::: "memory");

  const int NT = 16;
#pragma unroll 1
  for (int kt = 0; kt < NT; kt++) {
    int buf = kt & 1;
    RD_A(0, buf); RD_B(blo, 0, buf);
    if (kt + 1 < NT) STG_A(kt + 1, 1, buf ^ 1);
    __builtin_amdgcn_s_barrier();
    asm volatile("" ::: "memory");
    MM(0, blo, 0);
    __builtin_amdgcn_s_barrier();
    asm volatile("" ::: "memory");
    RD_B(bhi, 1, buf);
    if (kt + 1 < NT) STG_B(kt + 1, 1, buf ^ 1);
    __builtin_amdgcn_s_barrier();
    asm volatile("" ::: "memory");
    MM(0, bhi, 1);
    __builtin_amdgcn_s_barrier();
    asm volatile("" ::: "memory");
    RD_A(1, buf);
    if (kt + 2 < NT) STG_B(kt + 2, 0, buf);
    __builtin_amdgcn_s_barrier();
    asm volatile("" ::: "memory");
    MM(1, bhi, 1);
    __builtin_amdgcn_s_barrier();
    asm volatile("" ::: "memory");
    if (kt + 2 < NT) STG_A(kt + 2, 0, buf);
    if (kt < NT - 2) {
      asm volatile("s_waitcnt vmcnt(4)" ::: "memory");
    } else if (kt == NT - 2) {
      asm volatile("s_waitcnt vmcnt(0)" ::: "memory");
    }
    __builtin_amdgcn_s_barrier();
    asm volatile("" ::: "memory");
    MM(1, blo, 0);
    __builtin_amdgcn_s_barrier();
    asm volatile("" ::: "memory");
  }

#pragma unroll
  for (int mf = 0; mf < 8; mf++) {
#pragma unroll
    for (int p = 0; p < 2; p++) {
      f32x4 uu = acc[mf][2 * p], vv = acc[mf][2 * p + 1];
      int hcol = (nt * 8 + wn * 2 + p) * 16 + l15;
#pragma unroll
      for (int rr = 0; rr < 4; rr++) {
        int r_out = row0 + wr * 128 + mf * 16 + g4 * 4 + rr;
        float xx = uu[rr];
        float hh = (xx / (1.f + __expf(-xx))) * vv[rr];
        h_buf[(size_t)r_out * H_DIM + hcol] = f2bf(hh);
      }
    }
  }
}

// ---------------- pass B: y = h*W3, K-split x2 -> bf16 partials. Verified 4-phase, NT=16 ----------------
__global__ __launch_bounds__(512, 2) void ffn2_kernel(
    const unsigned short* __restrict__ h_buf, const unsigned short* __restrict__ W3t,
    unsigned short* __restrict__ y_buf,   // [2][MAXP][1024] partials (75.5 MB)
    const int* __restrict__ tile2e, const int* __restrict__ tile_row0) {
  extern __shared__ char lds[];
  char* ldsB = lds + 65536;
  const int NWG = MAXT * 8;  // 576, %8==0 : f x 4 nt x 2 kseg
  int orig = blockIdx.x;
  int wg = (orig & 7) * (NWG >> 3) + (orig >> 3);
  int f = wg >> 3;
  int r8 = wg & 7;
  int nt = r8 >> 1, kseg = r8 & 1;
  int e = tile2e[f];
  if (e < 0) return;
  int row0 = tile_row0[f];

  int tid = threadIdx.x;
  int w = tid >> 6, lane = tid & 63;
  int l15 = lane & 15, g4 = lane >> 4;
  int wr = w >> 2, wn = w & 3;

  int s0 = w * 64 + lane;
  int r0_ = s0 >> 3, c0_ = s0 & 7;
  int kc = c0_ ^ (r0_ & 7);
  const char* gA[2][2];
  const char* gB[2][2];
  const char* W3e = (const char*)W3t + (size_t)e * 1024 * 4096;
  int kbase = kseg * 2048;  // byte offset: 1024 k-elems * 2B
#pragma unroll
  for (int h = 0; h < 2; h++) {
    gA[h][0] = (const char*)h_buf + (size_t)(row0 + h * 128 + r0_) * 4096 + kbase + kc * 16;
    gA[h][1] = (const char*)h_buf + (size_t)(row0 + h * 128 + r0_ + 64) * 4096 + kbase + kc * 16;
    gB[h][0] = W3e + (size_t)(nt * 256 + h * 128 + r0_) * 4096 + kbase + kc * 16;
    gB[h][1] = W3e + (size_t)(nt * 256 + h * 128 + r0_ + 64) * 4096 + kbase + kc * 16;
  }

  auto STG_A = [&](int kt, int h, int buf) {
    char* d = lds + buf * 32768 + h * 16384 + w * 1024;
    gload16(gA[h][0] + kt * 128, d);
    gload16(gA[h][1] + kt * 128, d + 8192);
  };
  auto STG_B = [&](int kt, int h, int buf) {
    char* d = ldsB + buf * 32768 + h * 16384 + w * 1024;
    gload16(gB[h][0] + kt * 128, d);
    gload16(gB[h][1] + kt * 128, d + 8192);
  };

  int sw = l15 & 7;
  int cbase = (sw >> 2) * 64 + ((g4 ^ (sw & 3)) * 16);
  int aRow = wr * 16384 + l15 * 128;
  int bRow = 65536 + wn * 8192 + l15 * 128;

  f32x4 acc[8][4];
#pragma unroll
  for (int i = 0; i < 8; i++)
#pragma unroll
    for (int j = 0; j < 4; j++) acc[i][j] = (f32x4){0.f, 0.f, 0.f, 0.f};

  short8 a[4][2], blo[2][2], bhi[2][2];
  auto RD_A = [&](int mq, int buf) {
    const char* base = lds + buf * 32768 + aRow + mq * 8192;
#pragma unroll
    for (int m2 = 0; m2 < 4; m2++)
#pragma unroll
      for (int ks = 0; ks < 2; ks++)
        a[m2][ks] = *(const short8*)(base + m2 * 2048 + (cbase ^ (ks << 6)));
  };
  auto RD_B = [&](short8 (&b)[2][2], int nq, int buf) {
    const char* base = lds + buf * 32768 + bRow + nq * 4096;
#pragma unroll
    for (int n2 = 0; n2 < 2; n2++)
#pragma unroll
      for (int ks = 0; ks < 2; ks++)
        b[n2][ks] = *(const short8*)(base + n2 * 2048 + (cbase ^ (ks << 6)));
  };
  auto MM = [&](int mq, short8 (&b)[2][2], int nq) {
    __builtin_amdgcn_s_setprio(1);
#pragma unroll
    for (int m2 = 0; m2 < 4; m2++)
#pragma unroll
      for (int n2 = 0; n2 < 2; n2++)
#pragma unroll
        for (int ks = 0; ks < 2; ks++)
          acc[mq * 4 + m2][nq * 2 + n2] = __builtin_amdgcn_mfma_f32_16x16x32_bf16(
              a[m2][ks], b[n2][ks], acc[mq * 4 + m2][nq * 2 + n2], 0, 0, 0);
    __builtin_amdgcn_s_setprio(0);
  };

  STG_A(0, 0, 0); STG_A(0, 1, 0); STG_B(0, 0, 0); STG_B(0, 1, 0);
  STG_B(1, 0, 1); STG_A(1, 0, 1);
  asm volatile("s_waitcnt vmcnt(4)" ::: "memory");
  __builtin_amdgcn_s_barrier();
  asm volatile("" ::: "memory");

  const int NT = 16;
#pragma unroll 1
  for (int kt = 0; kt < NT; kt++) {
    int buf = kt & 1;
    RD_A(0, buf); RD_B(blo, 0, buf);
    if (kt + 1 < NT) STG_A(kt + 1, 1, buf ^ 1);
    __builtin_amdgcn_s_barrier();
    asm volatile("" ::: "memory");
    MM(0, blo, 0);
    __builtin_amdgcn_s_barrier();
    asm volatile("" ::: "memory");
    RD_B(bhi, 1, buf);
    if (kt + 1 < NT) STG_B(kt + 1, 1, buf ^ 1);
    __builtin_amdgcn_s_barrier();
    asm volatile("" ::: "memory");
    MM(0, bhi, 1);
    __builtin_amdgcn_s_barrier();
    asm volatile("" ::: "memory");
    RD_A(1, buf);
    if (kt + 2 < NT) STG_B(kt + 2, 0, buf);
    __builtin_amdgcn_s_barrier();
    asm volatile("" ::: "memory");
    MM(1, bhi, 1);
    __builtin_amdgcn_s_barrier();
    asm volatile("" ::: "memory");
    if (kt + 2 < NT) STG_A(kt + 2, 0, buf);
    if (kt < NT - 2) {
      asm volatile("s_waitcnt vmcnt(4)" ::: "memory");
    } else if (kt == NT - 2) {
      asm volatile("s_waitcnt vmcnt(0)" ::: "memory");
    }
    __builtin_amdgcn_s_barrier();
    asm volatile("" ::: "memory");
    MM(1, blo, 0);
    __builtin_amdgcn_s_barrier();
    asm volatile("" ::: "memory");
  }

  unsigned short* yseg = y_buf + (size_t)kseg * MAXP * 1024;
#pragma unroll
  for (int mf = 0; mf < 8; mf++) {
#pragma unroll
    for (int nf = 0; nf < 4; nf++) {
      int col = nt * 256 + wn * 64 + nf * 16 + l15;
#pragma unroll
      for (int rr = 0; rr < 4; rr++) {
        int pos = row0 + wr * 128 + mf * 16 + g4 * 4 + rr;
        yseg[(size_t)pos * D_DIM + col] = f2bf(acc[mf][nf][rr]);
      }
    }
  }
}

// ---------------- combine: out[t] = w0*(y0[p0]+y1[p0]) + w1*(y0[p1]+y1[p1]) ----------------
__global__ void combine_kernel(const unsigned short* __restrict__ y_buf,
                               const int2* __restrict__ tok_pos, const float* __restrict__ tok_w,
                               float* __restrict__ out) {
  int t = blockIdx.x * 2 + (threadIdx.x >> 7);
  int c = (threadIdx.x & 127) * 8;
  int2 p = tok_pos[t];
  float w0 = tok_w[2 * t], w1 = tok_w[2 * t + 1];
  const unsigned short* y1 = y_buf + (size_t)MAXP * 1024;
  u16x8 a0 = *(const u16x8*)(y_buf + (size_t)p.x * D_DIM + c);
  u16x8 a1 = *(const u16x8*)(y1 + (size_t)p.x * D_DIM + c);
  u16x8 b0 = *(const u16x8*)(y_buf + (size_t)p.y * D_DIM + c);
  u16x8 b1 = *(const u16x8*)(y1 + (size_t)p.y * D_DIM + c);
  float o[8];
#pragma unroll
  for (int k = 0; k < 8; k++)
    o[k] = w0 * (bf2f(a0[k]) + bf2f(a1[k])) + w1 * (bf2f(b0[k]) + bf2f(b1[k]));
  float4* op = (float4*)(out + (size_t)t * D_DIM + c);
  op[0] = make_float4(o[0], o[1], o[2], o[3]);
  op[1] = make_float4(o[4], o[5], o[6], o[7]);
}

// ---------------- launch ----------------
extern "C" void kernel_launch(void* const* d_in, const int* in_sizes, int n_in,
                              void* d_out, int out_size, void* d_ws, size_t ws_size,
                              hipStream_t stream) {
  const float* x  = (const float*)d_in[0];
  const float* Wg = (const float*)d_in[1];
  const float* W1 = (const float*)d_in[2];
  const float* W2 = (const float*)d_in[3];
  const float* W3 = (const float*)d_in[4];
  float* out = (float*)d_out;

  char* ws = (char*)d_ws;
  size_t off = 0;
  auto alloc = [&](size_t bytes) -> char* {
    char* p = ws + off; off += (bytes + 255) & ~(size_t)255; return p;
  };

  int*            poffs      = (int*)alloc(16 * 4);
  int*            tile2e     = (int*)alloc(80 * 4);
  int*            tile_row0  = (int*)alloc(80 * 4);
  int*            chunk_base = (int*)alloc(NCHUNK * E_NUM * 4);
  int*            tok_e01    = (int*)alloc(T_TOKENS * 4);
  float*          tok_w      = (float*)alloc(T_TOKENS * 8);
  int2*           tok_pos    = (int2*)alloc(T_TOKENS * 8);
  int*            pair_tok   = (int*)alloc(MAXP * 4);
  unsigned short* xb         = (unsigned short*)alloc((size_t)T_TOKENS * D_DIM * 2);    // 16 MB
  unsigned short* Bcat       = (unsigned short*)alloc((size_t)E_NUM * 4096 * 1024 * 2); // 64 MB, after xb
  unsigned short* W3t        = (unsigned short*)alloc((size_t)E_NUM * D_DIM * H_DIM * 2);
  unsigned short* h_buf      = (unsigned short*)alloc((size_t)MAXP * H_DIM * 2);
  // y_buf needs 2 * MAXP * 1024 * 2B = 75.5 MB: xb(16MB)+Bcat(64MB) contiguous dead
  // region after ffn1 = 80 MB. W3t untouched. (round-10 lesson: never overrun into W3t)
  unsigned short* y_buf      = xb;

  hipFuncSetAttribute((const void*)ffn1_kernel, hipFuncAttributeMaxDynamicSharedMemorySize, 131072);
  hipFuncSetAttribute((const void*)ffn2_kernel, hipFuncAttributeMaxDynamicSharedMemorySize, 131072);

  hipMemsetAsync(pair_tok, 0, MAXP * 4, stream);

  router_kernel<<<T_TOKENS / 4, 256, 0, stream>>>(x, Wg, tok_e01, tok_w, xb);
  hist_kernel<<<1, 1024, 0, stream>>>(tok_e01, poffs, tile2e, tile_row0, chunk_base);
  assign_kernel<<<NCHUNK, 256, 0, stream>>>(tok_e01, chunk_base, pair_tok, tok_pos);
  cast_w12_kernel<<<dim3(H_DIM / 64, D_DIM / 64, E_NUM * 2), 256, 0, stream>>>(W1, W2, Bcat);
  cast_w3_kernel<<<dim3(D_DIM / 64, H_DIM / 64, E_NUM), 256, 0, stream>>>(W3, W3t);

  ffn1_kernel<<<dim3(MAXT * 16), 512, 131072, stream>>>(xb, Bcat, h_buf, pair_tok, tile2e, tile_row0);
  ffn2_kernel<<<dim3(MAXT * 8), 512, 131072, stream>>>(h_buf, W3t, y_buf, tile2e, tile_row0);
  combine_kernel<<<T_TOKENS / 2, 256, 0, stream>>>(y_buf, tok_pos, tok_w, out);
}